// Round 1
// baseline (2015.429 us; speedup 1.0000x reference)
//
#include <hip/hip_runtime.h>
#include <hip/hip_bf16.h>
#include <math.h>

// Problem constants
#define Dd   128          // out_dim
#define Hh   4            // heads
#define DKk  32           // d_k
#define Mm   5            // types
#define NNn  15           // N
#define Bb   1024         // batch
#define Nn   64           // n
#define MN   75           // M*NN
#define BN   65536        // Bb*Nn
#define RSQRT_DK 0.17677669529663687f   // 1/sqrt(32)

// ---------------------------------------------------------------------------
// Kernel 1: per-b projections.
//   nim[m][d][N] = sum_n node[d,b,n] * WW[b,m,n,N]
//   for P in {K,Q,msg}: x[m][d][N] = bias + sum_e W[m,d,e]*nim[m][e][N]
//     K/Q: out[d][i] = sum_{m,N} x[m][d][N] * mask[m*15+N][i]   (permuted flatten)
//     msg: out[dd][i] = sum_j  x_flat[dd*75+j] * mask[j][i]     (direct flatten)
// ---------------------------------------------------------------------------
__global__ __launch_bounds__(512) void k1_proj(
    const float* __restrict__ node,   // (128,1024,64)
    const float* __restrict__ WW,     // (1024,5,64,15)
    const float* __restrict__ maskm,  // (75,64)
    const float* __restrict__ WK, const float* __restrict__ bK,
    const float* __restrict__ WQ, const float* __restrict__ bQ,
    const float* __restrict__ WM, const float* __restrict__ bM,
    float* __restrict__ Kout, float* __restrict__ Qout, float* __restrict__ Mout)
{
    const int b = blockIdx.x;
    const int tid = threadIdx.x;
    __shared__ float node_s[Dd * Nn];       // 8192 f  (32 KB)
    __shared__ float WW_s[Mm * Nn * NNn];   // 4800 f
    __shared__ float mask_s[MN * Nn];       // 4800 f
    __shared__ float nim[Mm * Dd * NNn];    // 9600 f
    __shared__ float x_s[Mm * Dd * NNn];    // 9600 f   total ~147.9 KB

    for (int i = tid; i < Dd * Nn; i += 512)
        node_s[i] = node[(size_t)(i >> 6) * BN + b * 64 + (i & 63)];
    for (int i = tid; i < Mm * Nn * NNn; i += 512)
        WW_s[i] = WW[(size_t)b * (Mm * Nn * NNn) + i];
    for (int i = tid; i < MN * Nn; i += 512)
        mask_s[i] = maskm[i];
    __syncthreads();

    // nim
    for (int i = tid; i < Mm * Dd * NNn; i += 512) {
        int m = i / (Dd * NNn);
        int r = i - m * (Dd * NNn);
        int d = r / NNn, N = r - d * NNn;
        const float* wp = &WW_s[m * (Nn * NNn) + N];  // stride NNn over n
        const float* np = &node_s[d * Nn];
        float acc = 0.f;
        #pragma unroll
        for (int n = 0; n < Nn; ++n) acc += np[n] * wp[n * NNn];
        nim[i] = acc;
    }
    __syncthreads();

    for (int P = 0; P < 3; ++P) {
        const float* W    = (P == 0) ? WK : (P == 1) ? WQ : WM;
        const float* bias = (P == 0) ? bK : (P == 1) ? bQ : bM;
        float* out        = (P == 0) ? Kout : (P == 1) ? Qout : Mout;

        for (int i = tid; i < Mm * Dd * NNn; i += 512) {
            int m = i / (Dd * NNn);
            int r = i - m * (Dd * NNn);
            int d = r / NNn, N = r - d * NNn;
            const float* wp = &W[(size_t)m * Dd * Dd + d * Dd];
            const float* np = &nim[m * (Dd * NNn) + N];   // stride NNn over e
            float acc = bias[m * Dd + d];
            #pragma unroll 8
            for (int e = 0; e < Dd; ++e) acc += wp[e] * np[e * NNn];
            x_s[i] = acc;
        }
        __syncthreads();

        for (int i = tid; i < Dd * Nn; i += 512) {
            int d = i >> 6, col = i & 63;
            float acc = 0.f;
            if (P < 2) {
                #pragma unroll
                for (int m = 0; m < Mm; ++m)
                    #pragma unroll
                    for (int N = 0; N < NNn; ++N)
                        acc += x_s[m * (Dd * NNn) + d * NNn + N] *
                               mask_s[(m * NNn + N) * Nn + col];
            } else {
                const float* xp = &x_s[d * MN];   // x flat (m,d,N) viewed as (128,75)
                #pragma unroll
                for (int j = 0; j < MN; ++j) acc += xp[j] * mask_s[j * Nn + col];
            }
            out[(size_t)b * (Dd * Nn) + i] = acc;
        }
        __syncthreads();
    }
}

// ---------------------------------------------------------------------------
// Kernel 2: per (b,h) attention + message mixing + GELU.
//   A[i][j] = sum_k Q[k,i]K[k,j]/sqrt(dk) + R ; softmax rows; nan->0
//   aw[i][j] = sm[i][j%64]*attn_mask[i][j]  (j in [0,256))
//   res2[k][j] = sum_kk Wcat[kk][4k+j/64] * msg[kk][j%64]  (flat == res[k*256+j])
//   B[k][i] = gelu( sum_j aw[i][j]*res2[k][j] )
// B overwrites Q's global slice (safe: block reads its own Q slice first).
// ---------------------------------------------------------------------------
__global__ __launch_bounds__(256) void k2_attn(
    const float* __restrict__ Kbuf,
    const float* Qbuf,                 // aliases Bout - no restrict
    const float* __restrict__ Mbuf,
    const float* __restrict__ R,       // (1024,4,64,64)
    const float* __restrict__ am,      // (64,256)
    const float* __restrict__ Wu, const float* __restrict__ Wd,
    const float* __restrict__ Wl, const float* __restrict__ Wr,
    float* Bout,                       // (1024,128,64), aliases Qbuf
    float* __restrict__ aw00)          // (64,256)
{
    const int b = blockIdx.x >> 2, h = blockIdx.x & 3;
    const int tid = threadIdx.x;
    __shared__ float Q_s[DKk * Nn];     // 2048 f
    __shared__ float K_s[DKk * Nn];     // 2048 f
    __shared__ float msg_s[DKk * Nn];   // 2048 f
    __shared__ float smT[Nn * 65];      // transposed scores, pitch 65
    __shared__ float res_s[Dd * Nn];    // 8192 f  (res2[k][j] = res_s[k*256+j])
    __shared__ float amT[256 * 65];     // transposed attn-mask / later awT
    // total ~140.5 KB

    const size_t base = (size_t)b * (Dd * Nn) + h * (DKk * Nn);
    for (int i = tid; i < DKk * Nn; i += 256) {
        Q_s[i]   = Qbuf[base + i];
        K_s[i]   = Kbuf[base + i];
        msg_s[i] = Mbuf[base + i];
    }
    for (int t = tid; t < Nn * 256; t += 256) {
        int i = t >> 8, j = t & 255;
        amT[j * 65 + i] = am[t];
    }
    __syncthreads();

    // A + R, stored transposed smT[j][i]
    const float* Rb = &R[((size_t)b * Hh + h) * (Nn * Nn)];
    for (int t = tid; t < Nn * Nn; t += 256) {
        int i = t >> 6, j = t & 63;       // lanes vary j -> coalesced R read
        float acc = 0.f;
        #pragma unroll
        for (int k = 0; k < DKk; ++k) acc += Q_s[k * Nn + i] * K_s[k * Nn + j];
        smT[j * 65 + i] = Rb[t] + acc * RSQRT_DK;
    }
    __syncthreads();

    // softmax over j for each row i: 4 threads per row, 16 cols each
    {
        int row = tid >> 2, part = tid & 3;
        float v[16];
        float mx = -INFINITY;
        #pragma unroll
        for (int jj = 0; jj < 16; ++jj) {
            v[jj] = smT[(part * 16 + jj) * 65 + row];
            mx = fmaxf(mx, v[jj]);
        }
        mx = fmaxf(mx, __shfl_xor(mx, 1));
        mx = fmaxf(mx, __shfl_xor(mx, 2));
        float s = 0.f;
        #pragma unroll
        for (int jj = 0; jj < 16; ++jj) { v[jj] = expf(v[jj] - mx); s += v[jj]; }
        s += __shfl_xor(s, 1);
        s += __shfl_xor(s, 2);
        float inv = 1.0f / s;
        #pragma unroll
        for (int jj = 0; jj < 16; ++jj) {
            float p = v[jj] * inv;
            smT[(part * 16 + jj) * 65 + row] = isnan(p) ? 0.f : p;
        }
    }
    __syncthreads();

    // awT[j][i] = smT[j%64][i] * amT[j][i]  (overwrite amT in place)
    for (int t = tid; t < 256 * Nn; t += 256) {
        int j = t >> 6, i = t & 63;
        amT[j * 65 + i] = smT[(j & 63) * 65 + i] * amT[j * 65 + i];
    }
    // res_s[q][nn] = sum_kk Wcat[kk][q] * msg[kk][nn]
    for (int t = tid; t < Dd * Nn; t += 256) {
        int q = t >> 6, nn = t & 63;
        const float* wsel = (q < 32) ? Wu : (q < 64) ? Wd : (q < 96) ? Wl : Wr;
        int qq = q & 31;
        float acc = 0.f;
        #pragma unroll
        for (int kk = 0; kk < DKk; ++kk) acc += wsel[kk * 32 + qq] * msg_s[kk * Nn + nn];
        res_s[t] = acc;
    }
    __syncthreads();

    // aw[0,0] output
    if (blockIdx.x == 0) {
        for (int t = tid; t < Nn * 256; t += 256) {
            int i = t >> 8, j = t & 255;
            aw00[t] = amT[j * 65 + i];
        }
    }

    // B[k][i] = gelu( sum_j awT[j][i] * res_s[k*256+j] )
    for (int t = tid; t < DKk * Nn; t += 256) {
        int k = t >> 6, i = t & 63;
        const float* rp = &res_s[k * 256];
        float acc = 0.f;
        #pragma unroll 8
        for (int j = 0; j < 256; ++j) acc += amT[j * 65 + i] * rp[j];
        float g = 0.5f * acc * (1.0f + erff(acc * 0.70710678118654752f));
        Bout[base + t] = g;
    }
}

// ---------------------------------------------------------------------------
// Kernel 3: per-b output projection + residual.
// ---------------------------------------------------------------------------
__global__ __launch_bounds__(512) void k3_out(
    const float* __restrict__ Bbuf,   // (1024,128,64)
    const float* __restrict__ WW,
    const float* __restrict__ maskm,
    const float* __restrict__ WB, const float* __restrict__ bB,
    const float* __restrict__ node,
    float* __restrict__ outp)         // (128,1024,64)
{
    const int b = blockIdx.x;
    const int tid = threadIdx.x;
    __shared__ float B_s[Dd * Nn];
    __shared__ float WW_s[Mm * Nn * NNn];
    __shared__ float mask_s[MN * Nn];
    __shared__ float t1[Mm * Dd * NNn];
    __shared__ float t2[Mm * Dd * NNn];

    for (int i = tid; i < Dd * Nn; i += 512) B_s[i] = Bbuf[(size_t)b * (Dd * Nn) + i];
    for (int i = tid; i < Mm * Nn * NNn; i += 512) WW_s[i] = WW[(size_t)b * (Mm * Nn * NNn) + i];
    for (int i = tid; i < MN * Nn; i += 512) mask_s[i] = maskm[i];
    __syncthreads();

    for (int i = tid; i < Mm * Dd * NNn; i += 512) {
        int m = i / (Dd * NNn);
        int r = i - m * (Dd * NNn);
        int d = r / NNn, N = r - d * NNn;
        const float* wp = &WW_s[m * (Nn * NNn) + N];
        const float* bp = &B_s[d * Nn];
        float acc = 0.f;
        #pragma unroll
        for (int n = 0; n < Nn; ++n) acc += bp[n] * wp[n * NNn];
        t1[i] = acc;
    }
    __syncthreads();

    for (int i = tid; i < Mm * Dd * NNn; i += 512) {
        int m = i / (Dd * NNn);
        int r = i - m * (Dd * NNn);
        int d = r / NNn, N = r - d * NNn;
        const float* wp = &WB[(size_t)m * Dd * Dd + d * Dd];
        const float* xp = &t1[m * (Dd * NNn) + N];
        float acc = bB[m * Dd + d];
        #pragma unroll 8
        for (int e = 0; e < Dd; ++e) acc += wp[e] * xp[e * NNn];
        t2[i] = acc;
    }
    __syncthreads();

    for (int i = tid; i < Dd * Nn; i += 512) {
        int d = i >> 6, col = i & 63;
        float acc = 0.f;
        #pragma unroll
        for (int m = 0; m < Mm; ++m)
            #pragma unroll
            for (int N = 0; N < NNn; ++N)
                acc += t2[m * (Dd * NNn) + d * NNn + N] *
                       mask_s[(m * NNn + N) * Nn + col];
        size_t gi = (size_t)d * BN + b * 64 + col;
        outp[gi] = acc + node[gi];
    }
}

extern "C" void kernel_launch(void* const* d_in, const int* in_sizes, int n_in,
                              void* d_out, int out_size, void* d_ws, size_t ws_size,
                              hipStream_t stream) {
    const float* node  = (const float*)d_in[0];
    const float* WW    = (const float*)d_in[1];
    const float* maskm = (const float*)d_in[2];
    const float* R     = (const float*)d_in[3];
    const float* am    = (const float*)d_in[4];
    const float* WK = (const float*)d_in[5];  const float* bK = (const float*)d_in[6];
    const float* WQ = (const float*)d_in[7];  const float* bQ = (const float*)d_in[8];
    const float* WM = (const float*)d_in[9];  const float* bM = (const float*)d_in[10];
    const float* WB = (const float*)d_in[11]; const float* bB = (const float*)d_in[12];
    const float* Wu = (const float*)d_in[13]; const float* Wd = (const float*)d_in[14];
    const float* Wl = (const float*)d_in[15]; const float* Wr = (const float*)d_in[16];

    float* out  = (float*)d_out;                 // (128,1024,64) = 8388608 f
    float* aw00 = out + (size_t)Dd * BN;         // (64,256)

    // scratch: K and Q in ws (32 MB each); message staged in d_out's out-region
    // (consumed by k2 before k3 overwrites it); B overwrites Q in place.
    float* Kbuf = (float*)d_ws;
    float* Qbuf = Kbuf + (size_t)Bb * Dd * Nn;
    float* Mbuf = out;                           // borrow out region for message
    float* Bbuf = Qbuf;                          // overlay

    k1_proj<<<Bb, 512, 0, stream>>>(node, WW, maskm, WK, bK, WQ, bQ, WM, bM,
                                    Kbuf, Qbuf, Mbuf);
    k2_attn<<<Bb * Hh, 256, 0, stream>>>(Kbuf, Qbuf, Mbuf, R, am,
                                         Wu, Wd, Wl, Wr, Bbuf, aw00);
    k3_out<<<Bb, 512, 0, stream>>>(Bbuf, WW, maskm, WB, bB, node, out);
}

// Round 2
// 803.913 us; speedup vs baseline: 2.5070x; 2.5070x over previous
//
#include <hip/hip_runtime.h>
#include <math.h>

#define Dd 128
#define Hh 4
#define DKk 32
#define Mm 5
#define NNn 15
#define Bb 1024
#define Nn 64
#define MN 75
#define BN 65536
#define RSQRT_DK 0.17677669529663687f

typedef __attribute__((ext_vector_type(8))) short bf16x8;
typedef __attribute__((ext_vector_type(4))) float f32x4;

__device__ __forceinline__ ushort f2bf(float x) {
    unsigned u = __float_as_uint(x);
    u = (u + 0x7fffu + ((u >> 16) & 1u)) >> 16;
    return (ushort)u;
}
__device__ __forceinline__ float bf2f(ushort h) {
    return __uint_as_float(((unsigned)h) << 16);
}
__device__ __forceinline__ void split2(float x, ushort& hi, ushort& lo) {
    hi = f2bf(x);
    lo = f2bf(x - bf2f(hi));
}
__device__ __forceinline__ f32x4 MFMA(bf16x8 a, bf16x8 b, f32x4 c) {
    return __builtin_amdgcn_mfma_f32_16x16x32_bf16(a, b, c, 0, 0, 0);
}

// ---------------------------------------------------------------------------
// k0: weight preprocessing (runs every call; tiny).
//  - split WK,WQ into bf16 hi/lo; WM,WB to bf16 hi
//  - mask -> bf16 hi/lo, padded to 96 rows (rows 75..95 = 0)
//  - bias terms folded through the mask matmul (b-independent, fp32 exact):
//      btP[d][i]  = sum_m bP[m][d] * sum_N mask[m*15+N][i]        (K/Q/B style)
//      btM[dd][i] = sum_j bMflat[dd*75+j] * mask[j][i]            (msg style)
// ---------------------------------------------------------------------------
__global__ void k0_prep(const float* __restrict__ maskm,
                        const float* __restrict__ WK, const float* __restrict__ bK,
                        const float* __restrict__ WQ, const float* __restrict__ bQ,
                        const float* __restrict__ WM, const float* __restrict__ bM,
                        const float* __restrict__ WB, const float* __restrict__ bB,
                        ushort* __restrict__ WKhi, ushort* __restrict__ WKlo,
                        ushort* __restrict__ WQhi, ushort* __restrict__ WQlo,
                        ushort* __restrict__ WMhi, ushort* __restrict__ WBhi,
                        ushort* __restrict__ maskhi, ushort* __restrict__ masklo,
                        float* __restrict__ btK, float* __restrict__ btQ,
                        float* __restrict__ btM, float* __restrict__ btB)
{
    int tid = blockIdx.x * blockDim.x + threadIdx.x;
    int nthr = gridDim.x * blockDim.x;
    const int NW = Mm * Dd * Dd;  // 81920
    for (int i = tid; i < NW; i += nthr) {
        split2(WK[i], WKhi[i], WKlo[i]);
        split2(WQ[i], WQhi[i], WQlo[i]);
        WMhi[i] = f2bf(WM[i]);
        WBhi[i] = f2bf(WB[i]);
    }
    for (int i = tid; i < 96 * 64; i += nthr) {
        float v = (i < MN * 64) ? maskm[i] : 0.f;
        split2(v, maskhi[i], masklo[i]);
    }
    for (int i = tid; i < 8192; i += nthr) {
        int d = i >> 6, col = i & 63;
        float aKv = 0.f, aQv = 0.f, aBv = 0.f;
        for (int m = 0; m < Mm; ++m) {
            float mrs = 0.f;
            for (int N = 0; N < NNn; ++N) mrs += maskm[(m * 15 + N) * 64 + col];
            aKv += bK[m * 128 + d] * mrs;
            aQv += bQ[m * 128 + d] * mrs;
            aBv += bB[m * 128 + d] * mrs;
        }
        btK[i] = aKv; btQ[i] = aQv; btB[i] = aBv;
        float aMv = 0.f;
        int dd = d;
        for (int j = 0; j < MN; ++j) {
            int f = dd * 75 + j;
            int m = f / 1920;
            int dloc = (f / 15) & 127;
            aMv += bM[m * 128 + dloc] * maskm[j * 64 + col];
        }
        btM[i] = aMv;
    }
}

// ---------------------------------------------------------------------------
// k1: per-b. K/Q via split-precision MFMA (== fp32 accuracy):
//   nim_m = node @ WW_m          (K=64, split x split, 3 passes)
//   nm_m  = nim_m @ mask_m       (K=15 pad 32, split)
//   K/Q  += W_P[m] @ nm_m        (K=128 over 4 e-blocks, split)
// msg path single-bf16:
//   x_m = WM[m] @ nim_m -> flat xM;  msg = xM(flat) @ mask  (+btM)
// K -> d_out (fp32), Q -> ws (fp32), msg -> ws (bf16).
// ---------------------------------------------------------------------------
__global__ __launch_bounds__(512, 4) void k1_proj(
    const float* __restrict__ node, const float* __restrict__ WW,
    const ushort* __restrict__ WKhi, const ushort* __restrict__ WKlo,
    const ushort* __restrict__ WQhi, const ushort* __restrict__ WQlo,
    const ushort* __restrict__ WMhi,
    const ushort* __restrict__ maskhi, const ushort* __restrict__ masklo,
    const float* __restrict__ btK, const float* __restrict__ btQ,
    const float* __restrict__ btM,
    float* __restrict__ Kout, float* __restrict__ Qout, ushort* __restrict__ msgB)
{
    const int b = blockIdx.x;
    const int tid = threadIdx.x;
    const int lane = tid & 63, w = tid >> 6;
    const int l15 = lane & 15, lq = lane >> 4;

    __shared__ ushort ndh[128 * 66], ndl[128 * 66];
    __shared__ ushort wwh[64 * 17], wwl[64 * 17];
    __shared__ ushort nih[128 * 17], nil_[128 * 17];
    __shared__ ushort nmh[32 * 66], nml[32 * 66];
    __shared__ ushort xM[9600];

    for (int i = tid; i < 8192; i += 512) {
        int d = i >> 6, n = i & 63;
        float v = node[(size_t)d * BN + b * 64 + n];
        split2(v, ndh[d * 66 + n], ndl[d * 66 + n]);
    }
    const f32x4 zz = {0.f, 0.f, 0.f, 0.f};
    f32x4 aK[4], aQ[4];
    for (int c = 0; c < 4; ++c) { aK[c] = zz; aQ[c] = zz; }
    __syncthreads();

    for (int m = 0; m < Mm; ++m) {
        // WW_m split -> LDS, pad col 15 = 0
        for (int i = tid; i < 64 * 17; i += 512) {
            int n = i / 17, N = i - n * 17;
            float v = (N < 15) ? WW[(((size_t)b * Mm + m) * 64 + n) * 15 + N] : 0.f;
            split2(v, wwh[i], wwl[i]);
        }
        __syncthreads();

        // nim (rows w*16..+16): split x split, 3 passes
        {
            f32x4 c = zz;
            for (int ks = 0; ks < 2; ++ks) {
                int k0 = ks * 32 + (lq << 3);
                int arow = w * 16 + l15;
                bf16x8 ah, al, bh, bl;
                #pragma unroll
                for (int t = 0; t < 8; ++t) {
                    ah[t] = (short)ndh[arow * 66 + k0 + t];
                    al[t] = (short)ndl[arow * 66 + k0 + t];
                    bh[t] = (short)wwh[(k0 + t) * 17 + l15];
                    bl[t] = (short)wwl[(k0 + t) * 17 + l15];
                }
                c = MFMA(ah, bh, c); c = MFMA(ah, bl, c); c = MFMA(al, bh, c);
            }
            #pragma unroll
            for (int t = 0; t < 4; ++t) {
                int r = w * 16 + lq * 4 + t;
                split2(c[t], nih[r * 17 + l15], nil_[r * 17 + l15]);
            }
        }
        __syncthreads();

        // msg-x: x_m = WMhi[m] @ nim_hi  -> xM flat (bf16)
        {
            f32x4 c = zz;
            const ushort* Wp = WMhi + m * 16384;
            for (int ks = 0; ks < 4; ++ks) {
                int k0 = ks * 32 + (lq << 3);
                bf16x8 a = *reinterpret_cast<const bf16x8*>(Wp + (size_t)(w * 16 + l15) * 128 + k0);
                bf16x8 bh;
                #pragma unroll
                for (int t = 0; t < 8; ++t) bh[t] = (short)nih[(k0 + t) * 17 + l15];
                c = MFMA(a, bh, c);
            }
            if (l15 < 15) {
                #pragma unroll
                for (int t = 0; t < 4; ++t) {
                    int d = w * 16 + lq * 4 + t;
                    xM[m * 1920 + d * 15 + l15] = f2bf(c[t]);
                }
            }
        }

        // mask B-frag for this wave's nm tile (ct = w&3), hoisted per m
        bf16x8 mfh, mfl;
        {
            int ct = w & 3;
            int k0 = lq << 3;
            #pragma unroll
            for (int t = 0; t < 8; ++t) {
                int kk = k0 + t;
                int row = (kk < 15) ? (m * 15 + kk) : 95;  // row 95 is zero
                mfh[t] = (short)maskhi[row * 64 + ct * 16 + l15];
                mfl[t] = (short)masklo[row * 64 + ct * 16 + l15];
            }
        }

        for (int eb = 0; eb < 4; ++eb) {
            // nm tile (rtl = w>>2, ct = w&3): rows e-local 0..31
            {
                int rtl = w >> 2, ct = w & 3;
                int e = eb * 32 + rtl * 16 + l15;
                int k0 = lq << 3;
                bf16x8 ah, al;
                #pragma unroll
                for (int t = 0; t < 8; ++t) {
                    int kk = k0 + t;
                    int cc = (kk < 15) ? kk : 15;  // nim col 15 == 0
                    ah[t] = (short)nih[e * 17 + cc];
                    al[t] = (short)nil_[e * 17 + cc];
                }
                f32x4 c = zz;
                c = MFMA(ah, mfh, c); c = MFMA(ah, mfl, c); c = MFMA(al, mfh, c);
                #pragma unroll
                for (int t = 0; t < 4; ++t) {
                    int r = rtl * 16 + lq * 4 + t;
                    split2(c[t], nmh[r * 66 + ct * 16 + l15], nml[r * 66 + ct * 16 + l15]);
                }
            }
            __syncthreads();
            // out accumulate: K/Q += W_P[m][:, eb*32..+32] @ nm
            {
                size_t aoff = (size_t)(w * 16 + l15) * 128 + eb * 32 + (lq << 3);
                bf16x8 kh = *reinterpret_cast<const bf16x8*>(WKhi + m * 16384 + aoff);
                bf16x8 kl = *reinterpret_cast<const bf16x8*>(WKlo + m * 16384 + aoff);
                bf16x8 qh = *reinterpret_cast<const bf16x8*>(WQhi + m * 16384 + aoff);
                bf16x8 ql = *reinterpret_cast<const bf16x8*>(WQlo + m * 16384 + aoff);
                int k0 = lq << 3;
                #pragma unroll
                for (int ct = 0; ct < 4; ++ct) {
                    bf16x8 bh, bl;
                    #pragma unroll
                    for (int t = 0; t < 8; ++t) {
                        bh[t] = (short)nmh[(k0 + t) * 66 + ct * 16 + l15];
                        bl[t] = (short)nml[(k0 + t) * 66 + ct * 16 + l15];
                    }
                    aK[ct] = MFMA(kh, bh, aK[ct]); aK[ct] = MFMA(kh, bl, aK[ct]); aK[ct] = MFMA(kl, bh, aK[ct]);
                    aQ[ct] = MFMA(qh, bh, aQ[ct]); aQ[ct] = MFMA(qh, bl, aQ[ct]); aQ[ct] = MFMA(ql, bh, aQ[ct]);
                }
            }
            __syncthreads();
        }
    }

    // store K (d_out region, fp32) and Q (ws, fp32) with bias terms
    #pragma unroll
    for (int ct = 0; ct < 4; ++ct) {
        #pragma unroll
        for (int t = 0; t < 4; ++t) {
            int d = w * 16 + lq * 4 + t;
            int col = ct * 16 + l15;
            size_t gi = (size_t)b * 8192 + d * 64 + col;
            Kout[gi] = aK[ct][t] + btK[d * 64 + col];
            Qout[gi] = aQ[ct][t] + btQ[d * 64 + col];
        }
    }

    // msg mask-GEMM (flat rows dd): msg = xM @ mask + btM  (single bf16)
    {
        f32x4 c[4] = {zz, zz, zz, zz};
        for (int ks = 0; ks < 3; ++ks) {
            int k0 = ks * 32 + (lq << 3);
            int dd = w * 16 + l15;
            bf16x8 a;
            #pragma unroll
            for (int t = 0; t < 8; ++t) {
                int j = k0 + t;
                a[t] = (j < 75) ? (short)xM[dd * 75 + j] : (short)0;
            }
            #pragma unroll
            for (int ct = 0; ct < 4; ++ct) {
                bf16x8 bh;
                #pragma unroll
                for (int t = 0; t < 8; ++t) bh[t] = (short)maskhi[(k0 + t) * 64 + ct * 16 + l15];
                c[ct] = MFMA(a, bh, c[ct]);
            }
        }
        #pragma unroll
        for (int ct = 0; ct < 4; ++ct) {
            #pragma unroll
            for (int t = 0; t < 4; ++t) {
                int dd = w * 16 + lq * 4 + t;
                int col = ct * 16 + l15;
                msgB[(size_t)b * 8192 + dd * 64 + col] = f2bf(c[ct][t] + btM[dd * 64 + col]);
            }
        }
    }
}

// ---------------------------------------------------------------------------
// k2: per (b,h), fp32, 512 thr, 66KB LDS (2 blocks/CU).
// Region reuse: r3 = {Q,K} then res_s; r2 = msg then awqT.
// ---------------------------------------------------------------------------
__global__ __launch_bounds__(512, 4) void k2_attn(
    const float* __restrict__ Kd, const float* __restrict__ Qd,
    ushort* msgB,  // read msg, write B (same slice per block)
    const float* __restrict__ R, const float* __restrict__ am,
    const float* __restrict__ Wu, const float* __restrict__ Wd2,
    const float* __restrict__ Wl, const float* __restrict__ Wr,
    float* __restrict__ aw00)
{
    const int b = blockIdx.x >> 2, h = blockIdx.x & 3;
    const int tid = threadIdx.x;
    __shared__ float smT[64 * 65];
    __shared__ float r2[64 * 65];
    __shared__ float r3[8192];

    const size_t base = (size_t)b * 8192 + h * 2048;
    for (int i = tid; i < 2048; i += 512) {
        r3[i] = Qd[base + i];
        r3[2048 + i] = Kd[base + i];
        r2[i] = bf2f(msgB[base + i]);
    }
    __syncthreads();

    const float* Rb = R + ((size_t)b * Hh + h) * 4096;
    {
        int j = tid & 63, ib = tid >> 6;
        float acc[8];
        #pragma unroll
        for (int it = 0; it < 8; ++it) acc[it] = 0.f;
        for (int k = 0; k < 32; ++k) {
            float kv = r3[2048 + k * 64 + j];
            #pragma unroll
            for (int it = 0; it < 8; ++it)
                acc[it] += r3[k * 64 + ib + it * 8] * kv;
        }
        #pragma unroll
        for (int it = 0; it < 8; ++it) {
            int i = ib + it * 8;
            smT[j * 65 + i] = Rb[i * 64 + j] + acc[it] * RSQRT_DK;
        }
    }
    __syncthreads();

    {   // softmax: 8 threads per row
        int row = tid >> 3, part = tid & 7;
        float v[8]; float mx = -INFINITY;
        #pragma unroll
        for (int jj = 0; jj < 8; ++jj) { v[jj] = smT[(part * 8 + jj) * 65 + row]; mx = fmaxf(mx, v[jj]); }
        mx = fmaxf(mx, __shfl_xor(mx, 1));
        mx = fmaxf(mx, __shfl_xor(mx, 2));
        mx = fmaxf(mx, __shfl_xor(mx, 4));
        float s = 0.f;
        #pragma unroll
        for (int jj = 0; jj < 8; ++jj) { v[jj] = expf(v[jj] - mx); s += v[jj]; }
        s += __shfl_xor(s, 1); s += __shfl_xor(s, 2); s += __shfl_xor(s, 4);
        float inv = 1.f / s;
        #pragma unroll
        for (int jj = 0; jj < 8; ++jj) {
            float p = v[jj] * inv;
            smT[(part * 8 + jj) * 65 + row] = isnan(p) ? 0.f : p;
        }
    }
    __syncthreads();

    // res2[k][jj] = sum_kk Wcat[kk][4k+(jj>>6)] * msg[kk][jj&63]  -> r3 (Q,K dead)
    for (int t = tid; t < 8192; t += 512) {
        int k = t >> 8, jj = t & 255;
        int q = (k << 2) + (jj >> 6), nn = jj & 63;
        const float* Wsel = (q < 32) ? Wu : (q < 64) ? Wd2 : (q < 96) ? Wl : Wr;
        int qq = q & 31;
        float acc = 0.f;
        #pragma unroll
        for (int kk = 0; kk < 32; ++kk) acc += Wsel[kk * 32 + qq] * r2[kk * 64 + nn];
        r3[t] = acc;
    }
    __syncthreads();

    float accB[4] = {0.f, 0.f, 0.f, 0.f};
    int kb = tid >> 6, icol = tid & 63;
    for (int q = 0; q < 4; ++q) {
        for (int t = tid; t < 4096; t += 512) {
            int j0 = t & 63, i = t >> 6;
            r2[j0 * 65 + i] = smT[j0 * 65 + i] * am[i * 256 + q * 64 + j0];
        }
        __syncthreads();
        if (blockIdx.x == 0) {
            for (int t = tid; t < 4096; t += 512) {
                int j0 = t & 63, i = t >> 6;
                aw00[(size_t)i * 256 + q * 64 + j0] = r2[j0 * 65 + i];
            }
        }
        #pragma unroll
        for (int it = 0; it < 4; ++it) {
            int k = kb + it * 8;
            float a = 0.f;
            #pragma unroll 8
            for (int j0 = 0; j0 < 64; ++j0)
                a += r2[j0 * 65 + icol] * r3[k * 256 + q * 64 + j0];
            accB[it] += a;
        }
        __syncthreads();
    }
    #pragma unroll
    for (int it = 0; it < 4; ++it) {
        int k = kb + it * 8;
        float x = accB[it];
        float g = 0.5f * x * (1.f + erff(x * 0.70710678118654752f));
        msgB[base + k * 64 + icol] = f2bf(g);
    }
}

// ---------------------------------------------------------------------------
// k3: per-b, single-bf16 MFMA with the same mask-first reorder:
//   t1_m = B @ WW_m;  out += WB[m] @ (t1_m @ mask_m);  + btB + residual
// ---------------------------------------------------------------------------
__global__ __launch_bounds__(512, 4) void k3_out(
    const ushort* __restrict__ Bbuf, const float* __restrict__ WW,
    const ushort* __restrict__ WBhi, const ushort* __restrict__ maskhi,
    const float* __restrict__ btB, const float* __restrict__ node,
    float* __restrict__ outp)
{
    const int b = blockIdx.x, tid = threadIdx.x;
    const int lane = tid & 63, w = tid >> 6, l15 = lane & 15, lq = lane >> 4;
    __shared__ ushort sB[128 * 66];
    __shared__ ushort wwh[64 * 17];
    __shared__ ushort t1[128 * 17];
    __shared__ ushort nm[32 * 66];

    for (int i = tid; i < 8192; i += 512) {
        int d = i >> 6, n = i & 63;
        sB[d * 66 + n] = Bbuf[(size_t)b * 8192 + i];
    }
    const f32x4 zz = {0.f, 0.f, 0.f, 0.f};
    f32x4 acc[4];
    for (int c = 0; c < 4; ++c) acc[c] = zz;
    __syncthreads();

    for (int m = 0; m < Mm; ++m) {
        for (int i = tid; i < 64 * 17; i += 512) {
            int n = i / 17, N = i - n * 17;
            wwh[i] = (N < 15) ? f2bf(WW[(((size_t)b * Mm + m) * 64 + n) * 15 + N]) : (ushort)0;
        }
        __syncthreads();
        {
            f32x4 c = zz;
            for (int ks = 0; ks < 2; ++ks) {
                int k0 = ks * 32 + (lq << 3);
                bf16x8 a, bh;
                #pragma unroll
                for (int t = 0; t < 8; ++t) {
                    a[t] = (short)sB[(w * 16 + l15) * 66 + k0 + t];
                    bh[t] = (short)wwh[(k0 + t) * 17 + l15];
                }
                c = MFMA(a, bh, c);
            }
            #pragma unroll
            for (int t = 0; t < 4; ++t)
                t1[(w * 16 + lq * 4 + t) * 17 + l15] = f2bf(c[t]);
        }
        __syncthreads();

        bf16x8 mfh;
        {
            int ct = w & 3;
            int k0 = lq << 3;
            #pragma unroll
            for (int t = 0; t < 8; ++t) {
                int kk = k0 + t;
                int row = (kk < 15) ? (m * 15 + kk) : 95;
                mfh[t] = (short)maskhi[row * 64 + ct * 16 + l15];
            }
        }
        for (int eb = 0; eb < 4; ++eb) {
            {
                int rtl = w >> 2, ct = w & 3;
                int e = eb * 32 + rtl * 16 + l15;
                int k0 = lq << 3;
                bf16x8 a;
                #pragma unroll
                for (int t = 0; t < 8; ++t) {
                    int kk = k0 + t;
                    int cc = (kk < 15) ? kk : 15;
                    a[t] = (short)t1[e * 17 + cc];
                }
                f32x4 c = zz;
                c = MFMA(a, mfh, c);
                #pragma unroll
                for (int t = 0; t < 4; ++t)
                    nm[(rtl * 16 + lq * 4 + t) * 66 + ct * 16 + l15] = f2bf(c[t]);
            }
            __syncthreads();
            {
                size_t aoff = (size_t)(w * 16 + l15) * 128 + eb * 32 + (lq << 3);
                bf16x8 a = *reinterpret_cast<const bf16x8*>(WBhi + m * 16384 + aoff);
                int k0 = lq << 3;
                #pragma unroll
                for (int ct = 0; ct < 4; ++ct) {
                    bf16x8 bh;
                    #pragma unroll
                    for (int t = 0; t < 8; ++t) bh[t] = (short)nm[(k0 + t) * 66 + ct * 16 + l15];
                    acc[ct] = MFMA(a, bh, acc[ct]);
                }
            }
            __syncthreads();
        }
    }
    #pragma unroll
    for (int ct = 0; ct < 4; ++ct) {
        #pragma unroll
        for (int t = 0; t < 4; ++t) {
            int d = w * 16 + lq * 4 + t;
            int col = ct * 16 + l15;
            size_t gi = (size_t)d * BN + b * 64 + col;
            outp[gi] = acc[ct][t] + btB[d * 64 + col] + node[gi];
        }
    }
}

extern "C" void kernel_launch(void* const* d_in, const int* in_sizes, int n_in,
                              void* d_out, int out_size, void* d_ws, size_t ws_size,
                              hipStream_t stream) {
    const float* node  = (const float*)d_in[0];
    const float* WW    = (const float*)d_in[1];
    const float* maskm = (const float*)d_in[2];
    const float* R     = (const float*)d_in[3];
    const float* am    = (const float*)d_in[4];
    const float* WK = (const float*)d_in[5];  const float* bK = (const float*)d_in[6];
    const float* WQ = (const float*)d_in[7];  const float* bQ = (const float*)d_in[8];
    const float* WM = (const float*)d_in[9];  const float* bM = (const float*)d_in[10];
    const float* WB = (const float*)d_in[11]; const float* bB = (const float*)d_in[12];
    const float* Wu = (const float*)d_in[13]; const float* Wd = (const float*)d_in[14];
    const float* Wl = (const float*)d_in[15]; const float* Wr = (const float*)d_in[16];

    float* out  = (float*)d_out;                 // K staging, then final out
    float* aw00 = out + (size_t)Dd * BN;         // disjoint tail of d_out

    char* W = (char*)d_ws;
    float*  Qbuf   = (float*)W;                          // 33,554,432 B
    ushort* msgB   = (ushort*)(W + 33554432);            // 16,777,216 B (msg, then B)
    ushort* WKhi   = (ushort*)(W + 50331648);
    ushort* WKlo   = WKhi + 81920;
    ushort* WQhi   = WKlo + 81920;
    ushort* WQlo   = WQhi + 81920;
    ushort* WMhi   = WQlo + 81920;
    ushort* WBhi   = WMhi + 81920;
    ushort* maskhi = WBhi + 81920;                       // 96*64
    ushort* masklo = maskhi + 6144;
    float*  btK    = (float*)(masklo + 6144);
    float*  btQ    = btK + 8192;
    float*  btM    = btQ + 8192;
    float*  btB    = btM + 8192;

    k0_prep<<<512, 256, 0, stream>>>(maskm, WK, bK, WQ, bQ, WM, bM, WB, bB,
                                     WKhi, WKlo, WQhi, WQlo, WMhi, WBhi,
                                     maskhi, masklo, btK, btQ, btM, btB);
    k1_proj<<<Bb, 512, 0, stream>>>(node, WW, WKhi, WKlo, WQhi, WQlo, WMhi,
                                    maskhi, masklo, btK, btQ, btM,
                                    out, Qbuf, msgB);
    k2_attn<<<Bb * Hh, 512, 0, stream>>>(out, Qbuf, msgB, R, am, Wu, Wd, Wl, Wr, aw00);
    k3_out<<<Bb, 512, 0, stream>>>(msgB, WW, WBhi, maskhi, btB, node, out);
}

// Round 3
// 517.664 us; speedup vs baseline: 3.8933x; 1.5530x over previous
//
#include <hip/hip_runtime.h>
#include <math.h>

#define Dd 128
#define Hh 4
#define DKk 32
#define Mm 5
#define NNn 15
#define Bb 1024
#define Nn 64
#define MN 75
#define BN 65536
#define RSQRT_DK 0.17677669529663687f

typedef __attribute__((ext_vector_type(8))) short bf16x8;
typedef __attribute__((ext_vector_type(4))) float f32x4;

__device__ __forceinline__ ushort f2bf(float x) {
    unsigned u = __float_as_uint(x);
    u = (u + 0x7fffu + ((u >> 16) & 1u)) >> 16;
    return (ushort)u;
}
__device__ __forceinline__ float bf2f(ushort h) {
    return __uint_as_float(((unsigned)h) << 16);
}
__device__ __forceinline__ void split2(float x, ushort& hi, ushort& lo) {
    hi = f2bf(x);
    lo = f2bf(x - bf2f(hi));
}
__device__ __forceinline__ f32x4 MFMA(bf16x8 a, bf16x8 b, f32x4 c) {
    return __builtin_amdgcn_mfma_f32_16x16x32_bf16(a, b, c, 0, 0, 0);
}

// ---------------------------------------------------------------------------
// k0: weight preprocessing (runs every call; tiny).
// ---------------------------------------------------------------------------
__global__ void k0_prep(const float* __restrict__ maskm,
                        const float* __restrict__ WK, const float* __restrict__ bK,
                        const float* __restrict__ WQ, const float* __restrict__ bQ,
                        const float* __restrict__ WM, const float* __restrict__ bM,
                        const float* __restrict__ WB, const float* __restrict__ bB,
                        const float* __restrict__ Wu, const float* __restrict__ Wd,
                        const float* __restrict__ Wl, const float* __restrict__ Wr,
                        ushort* __restrict__ WKhi, ushort* __restrict__ WKlo,
                        ushort* __restrict__ WQhi, ushort* __restrict__ WQlo,
                        ushort* __restrict__ WMhi, ushort* __restrict__ WBhi,
                        ushort* __restrict__ maskhi, ushort* __restrict__ masklo,
                        float* __restrict__ btK, float* __restrict__ btQ,
                        float* __restrict__ btM, float* __restrict__ btB,
                        ushort* __restrict__ WcatT)
{
    int tid = blockIdx.x * blockDim.x + threadIdx.x;
    int nthr = gridDim.x * blockDim.x;
    const int NW = Mm * Dd * Dd;  // 81920
    for (int i = tid; i < NW; i += nthr) {
        split2(WK[i], WKhi[i], WKlo[i]);
        split2(WQ[i], WQhi[i], WQlo[i]);
        WMhi[i] = f2bf(WM[i]);
        WBhi[i] = f2bf(WB[i]);
    }
    for (int i = tid; i < 96 * 64; i += nthr) {
        float v = (i < MN * 64) ? maskm[i] : 0.f;
        split2(v, maskhi[i], masklo[i]);
    }
    // WcatT[q][kk] bf16, [128][32]
    for (int i = tid; i < 4096; i += nthr) {
        int q = i >> 5, kk = i & 31;
        const float* Wsel = (q < 32) ? Wu : (q < 64) ? Wd : (q < 96) ? Wl : Wr;
        WcatT[i] = f2bf(Wsel[kk * 32 + (q & 31)]);
    }
    for (int i = tid; i < 8192; i += nthr) {
        int d = i >> 6, col = i & 63;
        float aKv = 0.f, aQv = 0.f, aBv = 0.f;
        for (int m = 0; m < Mm; ++m) {
            float mrs = 0.f;
            for (int N = 0; N < NNn; ++N) mrs += maskm[(m * 15 + N) * 64 + col];
            aKv += bK[m * 128 + d] * mrs;
            aQv += bQ[m * 128 + d] * mrs;
            aBv += bB[m * 128 + d] * mrs;
        }
        btK[i] = aKv; btQ[i] = aQv; btB[i] = aBv;
        float aMv = 0.f;
        int dd = d;
        for (int j = 0; j < MN; ++j) {
            int f = dd * 75 + j;
            int m = f / 1920;
            int dloc = (f / 15) & 127;
            aMv += bM[m * 128 + dloc] * maskm[j * 64 + col];
        }
        btM[i] = aMv;
    }
}

// ---------------------------------------------------------------------------
// k1: per-b projections via MFMA (unchanged from round 2).
// ---------------------------------------------------------------------------
__global__ __launch_bounds__(512, 4) void k1_proj(
    const float* __restrict__ node, const float* __restrict__ WW,
    const ushort* __restrict__ WKhi, const ushort* __restrict__ WKlo,
    const ushort* __restrict__ WQhi, const ushort* __restrict__ WQlo,
    const ushort* __restrict__ WMhi,
    const ushort* __restrict__ maskhi, const ushort* __restrict__ masklo,
    const float* __restrict__ btK, const float* __restrict__ btQ,
    const float* __restrict__ btM,
    float* __restrict__ Kout, float* __restrict__ Qout, ushort* __restrict__ msgB)
{
    const int b = blockIdx.x;
    const int tid = threadIdx.x;
    const int lane = tid & 63, w = tid >> 6;
    const int l15 = lane & 15, lq = lane >> 4;

    __shared__ ushort ndh[128 * 66], ndl[128 * 66];
    __shared__ ushort wwh[64 * 17], wwl[64 * 17];
    __shared__ ushort nih[128 * 17], nil_[128 * 17];
    __shared__ ushort nmh[32 * 66], nml[32 * 66];
    __shared__ ushort xM[9600];

    for (int i = tid; i < 8192; i += 512) {
        int d = i >> 6, n = i & 63;
        float v = node[(size_t)d * BN + b * 64 + n];
        split2(v, ndh[d * 66 + n], ndl[d * 66 + n]);
    }
    const f32x4 zz = {0.f, 0.f, 0.f, 0.f};
    f32x4 aK[4], aQ[4];
    for (int c = 0; c < 4; ++c) { aK[c] = zz; aQ[c] = zz; }
    __syncthreads();

    for (int m = 0; m < Mm; ++m) {
        for (int i = tid; i < 64 * 17; i += 512) {
            int n = i / 17, N = i - n * 17;
            float v = (N < 15) ? WW[(((size_t)b * Mm + m) * 64 + n) * 15 + N] : 0.f;
            split2(v, wwh[i], wwl[i]);
        }
        __syncthreads();

        {
            f32x4 c = zz;
            for (int ks = 0; ks < 2; ++ks) {
                int k0 = ks * 32 + (lq << 3);
                int arow = w * 16 + l15;
                bf16x8 ah, al, bh, bl;
                #pragma unroll
                for (int t = 0; t < 8; ++t) {
                    ah[t] = (short)ndh[arow * 66 + k0 + t];
                    al[t] = (short)ndl[arow * 66 + k0 + t];
                    bh[t] = (short)wwh[(k0 + t) * 17 + l15];
                    bl[t] = (short)wwl[(k0 + t) * 17 + l15];
                }
                c = MFMA(ah, bh, c); c = MFMA(ah, bl, c); c = MFMA(al, bh, c);
            }
            #pragma unroll
            for (int t = 0; t < 4; ++t) {
                int r = w * 16 + lq * 4 + t;
                split2(c[t], nih[r * 17 + l15], nil_[r * 17 + l15]);
            }
        }
        __syncthreads();

        {
            f32x4 c = zz;
            const ushort* Wp = WMhi + m * 16384;
            for (int ks = 0; ks < 4; ++ks) {
                int k0 = ks * 32 + (lq << 3);
                bf16x8 a = *reinterpret_cast<const bf16x8*>(Wp + (size_t)(w * 16 + l15) * 128 + k0);
                bf16x8 bh;
                #pragma unroll
                for (int t = 0; t < 8; ++t) bh[t] = (short)nih[(k0 + t) * 17 + l15];
                c = MFMA(a, bh, c);
            }
            if (l15 < 15) {
                #pragma unroll
                for (int t = 0; t < 4; ++t) {
                    int d = w * 16 + lq * 4 + t;
                    xM[m * 1920 + d * 15 + l15] = f2bf(c[t]);
                }
            }
        }

        bf16x8 mfh, mfl;
        {
            int ct = w & 3;
            int k0 = lq << 3;
            #pragma unroll
            for (int t = 0; t < 8; ++t) {
                int kk = k0 + t;
                int row = (kk < 15) ? (m * 15 + kk) : 95;
                mfh[t] = (short)maskhi[row * 64 + ct * 16 + l15];
                mfl[t] = (short)masklo[row * 64 + ct * 16 + l15];
            }
        }

        for (int eb = 0; eb < 4; ++eb) {
            {
                int rtl = w >> 2, ct = w & 3;
                int e = eb * 32 + rtl * 16 + l15;
                int k0 = lq << 3;
                bf16x8 ah, al;
                #pragma unroll
                for (int t = 0; t < 8; ++t) {
                    int kk = k0 + t;
                    int cc = (kk < 15) ? kk : 15;
                    ah[t] = (short)nih[e * 17 + cc];
                    al[t] = (short)nil_[e * 17 + cc];
                }
                f32x4 c = zz;
                c = MFMA(ah, mfh, c); c = MFMA(ah, mfl, c); c = MFMA(al, mfh, c);
                #pragma unroll
                for (int t = 0; t < 4; ++t) {
                    int r = rtl * 16 + lq * 4 + t;
                    split2(c[t], nmh[r * 66 + ct * 16 + l15], nml[r * 66 + ct * 16 + l15]);
                }
            }
            __syncthreads();
            {
                size_t aoff = (size_t)(w * 16 + l15) * 128 + eb * 32 + (lq << 3);
                bf16x8 kh = *reinterpret_cast<const bf16x8*>(WKhi + m * 16384 + aoff);
                bf16x8 kl = *reinterpret_cast<const bf16x8*>(WKlo + m * 16384 + aoff);
                bf16x8 qh = *reinterpret_cast<const bf16x8*>(WQhi + m * 16384 + aoff);
                bf16x8 ql = *reinterpret_cast<const bf16x8*>(WQlo + m * 16384 + aoff);
                int k0 = lq << 3;
                #pragma unroll
                for (int ct = 0; ct < 4; ++ct) {
                    bf16x8 bh, bl;
                    #pragma unroll
                    for (int t = 0; t < 8; ++t) {
                        bh[t] = (short)nmh[(k0 + t) * 66 + ct * 16 + l15];
                        bl[t] = (short)nml[(k0 + t) * 66 + ct * 16 + l15];
                    }
                    aK[ct] = MFMA(kh, bh, aK[ct]); aK[ct] = MFMA(kh, bl, aK[ct]); aK[ct] = MFMA(kl, bh, aK[ct]);
                    aQ[ct] = MFMA(qh, bh, aQ[ct]); aQ[ct] = MFMA(qh, bl, aQ[ct]); aQ[ct] = MFMA(ql, bh, aQ[ct]);
                }
            }
            __syncthreads();
        }
    }

    #pragma unroll
    for (int ct = 0; ct < 4; ++ct) {
        #pragma unroll
        for (int t = 0; t < 4; ++t) {
            int d = w * 16 + lq * 4 + t;
            int col = ct * 16 + l15;
            size_t gi = (size_t)b * 8192 + d * 64 + col;
            Kout[gi] = aK[ct][t] + btK[d * 64 + col];
            Qout[gi] = aQ[ct][t] + btQ[d * 64 + col];
        }
    }

    {
        f32x4 c[4] = {zz, zz, zz, zz};
        for (int ks = 0; ks < 3; ++ks) {
            int k0 = ks * 32 + (lq << 3);
            int dd = w * 16 + l15;
            bf16x8 a;
            #pragma unroll
            for (int t = 0; t < 8; ++t) {
                int j = k0 + t;
                a[t] = (j < 75) ? (short)xM[dd * 75 + j] : (short)0;
            }
            #pragma unroll
            for (int ct = 0; ct < 4; ++ct) {
                bf16x8 bh;
                #pragma unroll
                for (int t = 0; t < 8; ++t) bh[t] = (short)maskhi[(k0 + t) * 64 + ct * 16 + l15];
                c[ct] = MFMA(a, bh, c[ct]);
            }
        }
        #pragma unroll
        for (int ct = 0; ct < 4; ++ct) {
            #pragma unroll
            for (int t = 0; t < 4; ++t) {
                int dd = w * 16 + lq * 4 + t;
                int col = ct * 16 + l15;
                msgB[(size_t)b * 8192 + dd * 64 + col] = f2bf(c[ct][t] + btM[dd * 64 + col]);
            }
        }
    }
}

// ---------------------------------------------------------------------------
// k2 v3: per (b,h), MFMA everywhere.
//   S = QtK via split bf16 (3 passes)  -> ST fp32, softmax fp32
//   res = WcatT @ msg (single bf16)    -> resS bf16 [128][72]
//   B   = sum_q resq @ awq^T           -> fp32 C-regs, gelu, bf16 store
// aw00 written fp32 (block 0 only).
// ---------------------------------------------------------------------------
__global__ __launch_bounds__(512, 4) void k2_attn(
    const float* __restrict__ Kd, const float* __restrict__ Qd,
    ushort* msgB,  // read msg, write B (same slice per block)
    const float* __restrict__ R, const float* __restrict__ am,
    const ushort* __restrict__ WcatT, float* __restrict__ aw00)
{
    const int b = blockIdx.x >> 2, h = blockIdx.x & 3;
    const int tid = threadIdx.x;
    const int lane = tid & 63, w = tid >> 6;
    const int l15 = lane & 15, lq = lane >> 4;

    __shared__ ushort QTh[64 * 40], QTl[64 * 40];   // QT[i][k] pitch 40
    __shared__ ushort KTh[64 * 40], KTl[64 * 40];   // KT[j][k]
    __shared__ ushort msgT[64 * 40];                // msgT[nn][kk]
    __shared__ float  ST[64 * 65];                  // ST[j][i]
    __shared__ ushort resS[128 * 72];               // res[q'][nn]
    __shared__ ushort awq[64 * 72];                 // awq[i][j0] bf16
    // total 69,888 B -> 2 blocks/CU

    const size_t base = (size_t)b * 8192 + h * 2048;
    for (int i = tid; i < 2048; i += 512) {
        int d = i >> 6, n = i & 63;   // d: k-index 0..31, n: col 0..63
        ushort hi, lo;
        split2(Qd[base + i], hi, lo); QTh[n * 40 + d] = hi; QTl[n * 40 + d] = lo;
        split2(Kd[base + i], hi, lo); KTh[n * 40 + d] = hi; KTl[n * 40 + d] = lo;
        msgT[n * 40 + d] = msgB[base + i];
    }
    __syncthreads();

    const float* Rb = R + ((size_t)b * Hh + h) * 4096;
    // S tiles: wave w -> ti = w>>1, tj = (w&1)*2 + s
    {
        int ti = w >> 1;
        bf16x8 ah = *reinterpret_cast<const bf16x8*>(&QTh[(ti * 16 + l15) * 40 + lq * 8]);
        bf16x8 al = *reinterpret_cast<const bf16x8*>(&QTl[(ti * 16 + l15) * 40 + lq * 8]);
        #pragma unroll
        for (int s = 0; s < 2; ++s) {
            int tj = (w & 1) * 2 + s;
            bf16x8 bh = *reinterpret_cast<const bf16x8*>(&KTh[(tj * 16 + l15) * 40 + lq * 8]);
            bf16x8 bl = *reinterpret_cast<const bf16x8*>(&KTl[(tj * 16 + l15) * 40 + lq * 8]);
            f32x4 c = {0.f, 0.f, 0.f, 0.f};
            c = MFMA(ah, bh, c); c = MFMA(ah, bl, c); c = MFMA(al, bh, c);
            #pragma unroll
            for (int r = 0; r < 4; ++r) {
                int i = ti * 16 + lq * 4 + r, j = tj * 16 + l15;
                ST[j * 65 + i] = Rb[i * 64 + j] + c[r] * RSQRT_DK;
            }
        }
    }
    // res tiles: wave w -> qt = w, nt = 0..3
    {
        bf16x8 a = *reinterpret_cast<const bf16x8*>(WcatT + (w * 16 + l15) * 32 + lq * 8);
        #pragma unroll
        for (int nt = 0; nt < 4; ++nt) {
            bf16x8 bfr = *reinterpret_cast<const bf16x8*>(&msgT[(nt * 16 + l15) * 40 + lq * 8]);
            f32x4 c = {0.f, 0.f, 0.f, 0.f};
            c = MFMA(a, bfr, c);
            #pragma unroll
            for (int r = 0; r < 4; ++r)
                resS[(w * 16 + lq * 4 + r) * 72 + nt * 16 + l15] = f2bf(c[r]);
        }
    }
    __syncthreads();

    {   // softmax over j per row i: 8 threads/row
        int row = tid >> 3, part = tid & 7;
        float v[8]; float mx = -INFINITY;
        #pragma unroll
        for (int jj = 0; jj < 8; ++jj) { v[jj] = ST[(part * 8 + jj) * 65 + row]; mx = fmaxf(mx, v[jj]); }
        mx = fmaxf(mx, __shfl_xor(mx, 1));
        mx = fmaxf(mx, __shfl_xor(mx, 2));
        mx = fmaxf(mx, __shfl_xor(mx, 4));
        float s = 0.f;
        #pragma unroll
        for (int jj = 0; jj < 8; ++jj) { v[jj] = expf(v[jj] - mx); s += v[jj]; }
        s += __shfl_xor(s, 1); s += __shfl_xor(s, 2); s += __shfl_xor(s, 4);
        float inv = 1.f / s;
        #pragma unroll
        for (int jj = 0; jj < 8; ++jj) {
            float p = v[jj] * inv;
            ST[(part * 8 + jj) * 65 + row] = isnan(p) ? 0.f : p;
        }
    }
    __syncthreads();

    // B tiles: wave w -> kt = w>>2, it = w&3; accumulate over q
    const int kt = w >> 2, it = w & 3;
    f32x4 accB = {0.f, 0.f, 0.f, 0.f};
    for (int q = 0; q < 4; ++q) {
        for (int e = tid; e < 4096; e += 512) {
            int i = e >> 6, j0 = e & 63;
            float p = ST[j0 * 65 + i] * am[i * 256 + q * 64 + j0];
            awq[i * 72 + j0] = f2bf(p);
            if (blockIdx.x == 0) aw00[i * 256 + q * 64 + j0] = p;
        }
        __syncthreads();
        #pragma unroll
        for (int ks = 0; ks < 2; ++ks) {
            int row = 4 * (kt * 16 + l15) + q;
            bf16x8 a   = *reinterpret_cast<const bf16x8*>(&resS[row * 72 + ks * 32 + lq * 8]);
            bf16x8 bfr = *reinterpret_cast<const bf16x8*>(&awq[(it * 16 + l15) * 72 + ks * 32 + lq * 8]);
            accB = MFMA(a, bfr, accB);
        }
        __syncthreads();
    }

    #pragma unroll
    for (int r = 0; r < 4; ++r) {
        int k = kt * 16 + lq * 4 + r, i = it * 16 + l15;
        float x = accB[r];
        float g = 0.5f * x * (1.f + erff(x * 0.70710678118654752f));
        msgB[base + k * 64 + i] = f2bf(g);
    }
}

// ---------------------------------------------------------------------------
// k3: per-b output projection + residual (unchanged from round 2).
// ---------------------------------------------------------------------------
__global__ __launch_bounds__(512, 4) void k3_out(
    const ushort* __restrict__ Bbuf, const float* __restrict__ WW,
    const ushort* __restrict__ WBhi, const ushort* __restrict__ maskhi,
    const float* __restrict__ btB, const float* __restrict__ node,
    float* __restrict__ outp)
{
    const int b = blockIdx.x, tid = threadIdx.x;
    const int lane = tid & 63, w = tid >> 6, l15 = lane & 15, lq = lane >> 4;
    __shared__ ushort sB[128 * 66];
    __shared__ ushort wwh[64 * 17];
    __shared__ ushort t1[128 * 17];
    __shared__ ushort nm[32 * 66];

    for (int i = tid; i < 8192; i += 512) {
        int d = i >> 6, n = i & 63;
        sB[d * 66 + n] = Bbuf[(size_t)b * 8192 + i];
    }
    const f32x4 zz = {0.f, 0.f, 0.f, 0.f};
    f32x4 acc[4];
    for (int c = 0; c < 4; ++c) acc[c] = zz;
    __syncthreads();

    for (int m = 0; m < Mm; ++m) {
        for (int i = tid; i < 64 * 17; i += 512) {
            int n = i / 17, N = i - n * 17;
            wwh[i] = (N < 15) ? f2bf(WW[(((size_t)b * Mm + m) * 64 + n) * 15 + N]) : (ushort)0;
        }
        __syncthreads();
        {
            f32x4 c = zz;
            for (int ks = 0; ks < 2; ++ks) {
                int k0 = ks * 32 + (lq << 3);
                bf16x8 a, bh;
                #pragma unroll
                for (int t = 0; t < 8; ++t) {
                    a[t] = (short)sB[(w * 16 + l15) * 66 + k0 + t];
                    bh[t] = (short)wwh[(k0 + t) * 17 + l15];
                }
                c = MFMA(a, bh, c);
            }
            #pragma unroll
            for (int t = 0; t < 4; ++t)
                t1[(w * 16 + lq * 4 + t) * 17 + l15] = f2bf(c[t]);
        }
        __syncthreads();

        bf16x8 mfh;
        {
            int ct = w & 3;
            int k0 = lq << 3;
            #pragma unroll
            for (int t = 0; t < 8; ++t) {
                int kk = k0 + t;
                int row = (kk < 15) ? (m * 15 + kk) : 95;
                mfh[t] = (short)maskhi[row * 64 + ct * 16 + l15];
            }
        }
        for (int eb = 0; eb < 4; ++eb) {
            {
                int rtl = w >> 2, ct = w & 3;
                int e = eb * 32 + rtl * 16 + l15;
                int k0 = lq << 3;
                bf16x8 a;
                #pragma unroll
                for (int t = 0; t < 8; ++t) {
                    int kk = k0 + t;
                    int cc = (kk < 15) ? kk : 15;
                    a[t] = (short)t1[e * 17 + cc];
                }
                f32x4 c = zz;
                c = MFMA(a, mfh, c);
                #pragma unroll
                for (int t = 0; t < 4; ++t)
                    nm[(rtl * 16 + lq * 4 + t) * 66 + ct * 16 + l15] = f2bf(c[t]);
            }
            __syncthreads();
            {
                size_t aoff = (size_t)(w * 16 + l15) * 128 + eb * 32 + (lq << 3);
                bf16x8 a = *reinterpret_cast<const bf16x8*>(WBhi + m * 16384 + aoff);
                int k0 = lq << 3;
                #pragma unroll
                for (int ct = 0; ct < 4; ++ct) {
                    bf16x8 bh;
                    #pragma unroll
                    for (int t = 0; t < 8; ++t) bh[t] = (short)nm[(k0 + t) * 66 + ct * 16 + l15];
                    acc[ct] = MFMA(a, bh, acc[ct]);
                }
            }
            __syncthreads();
        }
    }
    #pragma unroll
    for (int ct = 0; ct < 4; ++ct) {
        #pragma unroll
        for (int t = 0; t < 4; ++t) {
            int d = w * 16 + lq * 4 + t;
            int col = ct * 16 + l15;
            size_t gi = (size_t)d * BN + b * 64 + col;
            outp[gi] = acc[ct][t] + btB[d * 64 + col] + node[gi];
        }
    }
}

extern "C" void kernel_launch(void* const* d_in, const int* in_sizes, int n_in,
                              void* d_out, int out_size, void* d_ws, size_t ws_size,
                              hipStream_t stream) {
    const float* node  = (const float*)d_in[0];
    const float* WW    = (const float*)d_in[1];
    const float* maskm = (const float*)d_in[2];
    const float* R     = (const float*)d_in[3];
    const float* am    = (const float*)d_in[4];
    const float* WK = (const float*)d_in[5];  const float* bK = (const float*)d_in[6];
    const float* WQ = (const float*)d_in[7];  const float* bQ = (const float*)d_in[8];
    const float* WM = (const float*)d_in[9];  const float* bM = (const float*)d_in[10];
    const float* WB = (const float*)d_in[11]; const float* bB = (const float*)d_in[12];
    const float* Wu = (const float*)d_in[13]; const float* Wd = (const float*)d_in[14];
    const float* Wl = (const float*)d_in[15]; const float* Wr = (const float*)d_in[16];

    float* out  = (float*)d_out;                 // K staging, then final out
    float* aw00 = out + (size_t)Dd * BN;         // disjoint tail of d_out

    char* W = (char*)d_ws;
    float*  Qbuf   = (float*)W;                          // 33,554,432 B
    ushort* msgB   = (ushort*)(W + 33554432);            // 16,777,216 B (msg, then B)
    ushort* WKhi   = (ushort*)(W + 50331648);
    ushort* WKlo   = WKhi + 81920;
    ushort* WQhi   = WKlo + 81920;
    ushort* WQlo   = WQhi + 81920;
    ushort* WMhi   = WQlo + 81920;
    ushort* WBhi   = WMhi + 81920;
    ushort* maskhi = WBhi + 81920;                       // 96*64
    ushort* masklo = maskhi + 6144;
    float*  btK    = (float*)(masklo + 6144);
    float*  btQ    = btK + 8192;
    float*  btM    = btQ + 8192;
    float*  btB    = btM + 8192;
    ushort* WcatT  = (ushort*)(btB + 8192);              // [128][32] bf16

    k0_prep<<<512, 256, 0, stream>>>(maskm, WK, bK, WQ, bQ, WM, bM, WB, bB,
                                     Wu, Wd, Wl, Wr,
                                     WKhi, WKlo, WQhi, WQlo, WMhi, WBhi,
                                     maskhi, masklo, btK, btQ, btM, btB, WcatT);
    k1_proj<<<Bb, 512, 0, stream>>>(node, WW, WKhi, WKlo, WQhi, WQlo, WMhi,
                                    maskhi, masklo, btK, btQ, btM,
                                    out, Qbuf, msgB);
    k2_attn<<<Bb * Hh, 512, 0, stream>>>(out, Qbuf, msgB, R, am, WcatT, aw00);
    k3_out<<<Bb, 512, 0, stream>>>(msgB, WW, WBhi, maskhi, btB, node, out);
}

// Round 4
// 290.287 us; speedup vs baseline: 6.9429x; 1.7833x over previous
//
#include <hip/hip_runtime.h>
#include <math.h>

#define Dd 128
#define Hh 4
#define DKk 32
#define Mm 5
#define NNn 15
#define Bb 1024
#define Nn 64
#define MN 75
#define BN 65536
#define RSQRT_DK 0.17677669529663687f

typedef __attribute__((ext_vector_type(8))) short bf16x8;
typedef __attribute__((ext_vector_type(4))) float f32x4;

__device__ __forceinline__ ushort f2bf(float x) {
    unsigned u = __float_as_uint(x);
    u = (u + 0x7fffu + ((u >> 16) & 1u)) >> 16;
    return (ushort)u;
}
__device__ __forceinline__ float bf2f(ushort h) {
    return __uint_as_float(((unsigned)h) << 16);
}
__device__ __forceinline__ void split2(float x, ushort& hi, ushort& lo) {
    hi = f2bf(x);
    lo = f2bf(x - bf2f(hi));
}
__device__ __forceinline__ f32x4 MFMA(bf16x8 a, bf16x8 b, f32x4 c) {
    return __builtin_amdgcn_mfma_f32_16x16x32_bf16(a, b, c, 0, 0, 0);
}

// ---------------------------------------------------------------------------
// k0: weight preprocessing (tiny, runs every call).
//  - WK/WQ split hi/lo bf16; WM/WB hi bf16
//  - mask row-major split (for k3) AND transposed split maskT[col][j] (for k1)
//  - folded bias terms btK/btQ/btM/btB; WcatT for k2
// ---------------------------------------------------------------------------
__global__ void k0_prep(const float* __restrict__ maskm,
                        const float* __restrict__ WK, const float* __restrict__ bK,
                        const float* __restrict__ WQ, const float* __restrict__ bQ,
                        const float* __restrict__ WM, const float* __restrict__ bM,
                        const float* __restrict__ WB, const float* __restrict__ bB,
                        const float* __restrict__ Wu, const float* __restrict__ Wd,
                        const float* __restrict__ Wl, const float* __restrict__ Wr,
                        ushort* __restrict__ WKhi, ushort* __restrict__ WKlo,
                        ushort* __restrict__ WQhi, ushort* __restrict__ WQlo,
                        ushort* __restrict__ WMhi, ushort* __restrict__ WBhi,
                        ushort* __restrict__ maskhi, ushort* __restrict__ masklo,
                        ushort* __restrict__ maskThi, ushort* __restrict__ maskTlo,
                        float* __restrict__ btK, float* __restrict__ btQ,
                        float* __restrict__ btM, float* __restrict__ btB,
                        ushort* __restrict__ WcatT)
{
    int tid = blockIdx.x * blockDim.x + threadIdx.x;
    int nthr = gridDim.x * blockDim.x;
    const int NW = Mm * Dd * Dd;  // 81920
    for (int i = tid; i < NW; i += nthr) {
        split2(WK[i], WKhi[i], WKlo[i]);
        split2(WQ[i], WQhi[i], WQlo[i]);
        WMhi[i] = f2bf(WM[i]);
        WBhi[i] = f2bf(WB[i]);
    }
    for (int i = tid; i < 96 * 64; i += nthr) {
        float v = (i < MN * 64) ? maskm[i] : 0.f;
        split2(v, maskhi[i], masklo[i]);
    }
    // transposed mask: maskT[col][j], j padded to 96
    for (int i = tid; i < 64 * 96; i += nthr) {
        int col = i / 96, j = i - col * 96;
        float v = (j < MN) ? maskm[j * 64 + col] : 0.f;
        split2(v, maskThi[i], maskTlo[i]);
    }
    // WcatT[q][kk] bf16, [128][32]
    for (int i = tid; i < 4096; i += nthr) {
        int q = i >> 5, kk = i & 31;
        const float* Wsel = (q < 32) ? Wu : (q < 64) ? Wd : (q < 96) ? Wl : Wr;
        WcatT[i] = f2bf(Wsel[kk * 32 + (q & 31)]);
    }
    for (int i = tid; i < 8192; i += nthr) {
        int d = i >> 6, col = i & 63;
        float aKv = 0.f, aQv = 0.f, aBv = 0.f;
        for (int m = 0; m < Mm; ++m) {
            float mrs = 0.f;
            for (int N = 0; N < NNn; ++N) mrs += maskm[(m * 15 + N) * 64 + col];
            aKv += bK[m * 128 + d] * mrs;
            aQv += bQ[m * 128 + d] * mrs;
            aBv += bB[m * 128 + d] * mrs;
        }
        btK[i] = aKv; btQ[i] = aQv; btB[i] = aBv;
        float aMv = 0.f;
        int dd = d;
        for (int j = 0; j < MN; ++j) {
            int f = dd * 75 + j;
            int m = f / 1920;
            int dloc = (f / 15) & 127;
            aMv += bM[m * 128 + dloc] * maskm[j * 64 + col];
        }
        btM[i] = aMv;
    }
}

// ---------------------------------------------------------------------------
// k1 v4: per-b projections, original contraction order, all-b128 operands.
//   phase1: nimT[m*16+N][e] (split)  = (node @ WW_m)^T
//   phase2: per P in {K,Q}, per d-half:
//             Yp[d'][m*15+N] = W_P[m] @ nim_m    (split, K=128)
//             P[d'][col]     = Yp @ maskT^T + bt (split, K=96) -> global fp32
//   phase3: msg (single bf16): xMp flat = WM@nim; msg = xMp @ maskT^T + btM
// LDS 74.75 KB -> 2 blocks/CU.
// ---------------------------------------------------------------------------
__global__ __launch_bounds__(512, 4) void k1_proj(
    const float* __restrict__ node, const float* __restrict__ WW,
    const ushort* __restrict__ WKhi, const ushort* __restrict__ WKlo,
    const ushort* __restrict__ WQhi, const ushort* __restrict__ WQlo,
    const ushort* __restrict__ WMhi,
    const ushort* __restrict__ maskThi, const ushort* __restrict__ maskTlo,
    const float* __restrict__ btK, const float* __restrict__ btQ,
    const float* __restrict__ btM,
    float* __restrict__ Kout, float* __restrict__ Qout, ushort* __restrict__ msgB)
{
    const int b = blockIdx.x;
    const int tid = threadIdx.x;
    const int lane = tid & 63, w = tid >> 6;
    const int l15 = lane & 15, lq = lane >> 4;

    __shared__ ushort nimTh[80 * 136];   // [m*16+N][e] pitch 136
    __shared__ ushort nimTl[80 * 136];
    __shared__ ushort wwTh[16 * 72];     // [N][n] pitch 72
    __shared__ ushort wwTl[16 * 72];
    __shared__ ushort arena[128 * 104];  // Yp hi(rows0-63)/lo | xMp[128][104]

    ushort* Yph = arena;
    ushort* Ypl = arena + 64 * 104;

    // zero nimT N=15 rows + arena pad cols 75..103 (one-time)
    for (int t = tid; t < 5 * 136; t += 512) {
        int mm = t / 136, e = t - mm * 136;
        nimTh[(mm * 16 + 15) * 136 + e] = 0;
        nimTl[(mm * 16 + 15) * 136 + e] = 0;
    }
    for (int t = tid; t < 128 * 29; t += 512) {
        int r = t / 29, cc = 75 + (t - r * 29);
        arena[r * 104 + cc] = 0;
    }

    const f32x4 zz = {0.f, 0.f, 0.f, 0.f};

    // ---- phase 1: nimT ----
    for (int m = 0; m < Mm; ++m) {
        if (m) __syncthreads();
        for (int t = tid; t < 960; t += 512) {
            int n = t / 15, N = t - n * 15;
            float v = WW[(((size_t)b * Mm + m) * 64 + n) * 15 + N];
            split2(v, wwTh[N * 72 + n], wwTl[N * 72 + n]);
        }
        __syncthreads();
        f32x4 c = zz;
        #pragma unroll
        for (int ks = 0; ks < 2; ++ks) {
            int k0 = ks * 32 + lq * 8;
            const float* np = node + (size_t)(w * 16 + l15) * BN + b * 64 + k0;
            float tmp[8];
            *(float4*)tmp       = *(const float4*)np;
            *(float4*)(tmp + 4) = *(const float4*)(np + 4);
            bf16x8 ah, al;
            #pragma unroll
            for (int j = 0; j < 8; ++j) {
                ushort h_, l_; split2(tmp[j], h_, l_);
                ah[j] = (short)h_; al[j] = (short)l_;
            }
            bf16x8 bh = *reinterpret_cast<const bf16x8*>(&wwTh[l15 * 72 + k0]);
            bf16x8 bl = *reinterpret_cast<const bf16x8*>(&wwTl[l15 * 72 + k0]);
            c = MFMA(ah, bh, c); c = MFMA(ah, bl, c); c = MFMA(al, bh, c);
        }
        if (l15 < 15) {
            #pragma unroll
            for (int t = 0; t < 4; ++t) {
                int e = w * 16 + lq * 4 + t;
                split2(c[t], nimTh[(m * 16 + l15) * 136 + e],
                             nimTl[(m * 16 + l15) * 136 + e]);
            }
        }
    }
    __syncthreads();

    // ---- phase 2: K and Q ----
    for (int P = 0; P < 2; ++P) {
        const ushort* Whi = P ? WQhi : WKhi;
        const ushort* Wlo = P ? WQlo : WKlo;
        const float*  bt  = P ? btQ  : btK;
        float* Pout       = P ? Qout : Kout;
        for (int half = 0; half < 2; ++half) {
            // Y GEMM: units (rt 0..3) x (m 0..4)
            for (int u = w; u < 20; u += 8) {
                int rt = u & 3, m = u >> 2;
                int dd = half * 64 + rt * 16 + l15;
                f32x4 c = zz;
                #pragma unroll
                for (int ks = 0; ks < 4; ++ks) {
                    int k0 = ks * 32 + lq * 8;
                    bf16x8 ah = *reinterpret_cast<const bf16x8*>(&Whi[m * 16384 + (size_t)dd * 128 + k0]);
                    bf16x8 al = *reinterpret_cast<const bf16x8*>(&Wlo[m * 16384 + (size_t)dd * 128 + k0]);
                    bf16x8 bh = *reinterpret_cast<const bf16x8*>(&nimTh[(m * 16 + l15) * 136 + k0]);
                    bf16x8 bl = *reinterpret_cast<const bf16x8*>(&nimTl[(m * 16 + l15) * 136 + k0]);
                    c = MFMA(ah, bh, c); c = MFMA(ah, bl, c); c = MFMA(al, bh, c);
                }
                if (l15 < 15) {
                    int j = m * 15 + l15;
                    #pragma unroll
                    for (int t = 0; t < 4; ++t) {
                        int r = rt * 16 + lq * 4 + t;
                        split2(c[t], Yph[r * 104 + j], Ypl[r * 104 + j]);
                    }
                }
            }
            __syncthreads();
            // mask GEMM: 16 tiles, 2 per wave
            #pragma unroll
            for (int s = 0; s < 2; ++s) {
                int u = w * 2 + s;
                int rt = u & 3, ct = u >> 2;
                f32x4 c = zz;
                #pragma unroll
                for (int ks = 0; ks < 3; ++ks) {
                    int k0 = ks * 32 + lq * 8;
                    bf16x8 ah = *reinterpret_cast<const bf16x8*>(&Yph[(rt * 16 + l15) * 104 + k0]);
                    bf16x8 al = *reinterpret_cast<const bf16x8*>(&Ypl[(rt * 16 + l15) * 104 + k0]);
                    bf16x8 bh = *reinterpret_cast<const bf16x8*>(&maskThi[(ct * 16 + l15) * 96 + k0]);
                    bf16x8 bl = *reinterpret_cast<const bf16x8*>(&maskTlo[(ct * 16 + l15) * 96 + k0]);
                    c = MFMA(ah, bh, c); c = MFMA(ah, bl, c); c = MFMA(al, bh, c);
                }
                #pragma unroll
                for (int t = 0; t < 4; ++t) {
                    int d = half * 64 + rt * 16 + lq * 4 + t;
                    int col = ct * 16 + l15;
                    size_t gi = (size_t)b * 8192 + (size_t)d * 64 + col;
                    Pout[gi] = c[t] + bt[d * 64 + col];
                }
            }
            __syncthreads();
        }
    }

    // ---- phase 3: msg (single bf16) ----
    for (int half = 0; half < 2; ++half) {
        for (int u = w; u < 20; u += 8) {
            int rt = u & 3, m = u >> 2;
            int dd = half * 64 + rt * 16 + l15;
            f32x4 c = zz;
            #pragma unroll
            for (int ks = 0; ks < 4; ++ks) {
                int k0 = ks * 32 + lq * 8;
                bf16x8 a  = *reinterpret_cast<const bf16x8*>(&WMhi[m * 16384 + (size_t)dd * 128 + k0]);
                bf16x8 bh = *reinterpret_cast<const bf16x8*>(&nimTh[(m * 16 + l15) * 136 + k0]);
                c = MFMA(a, bh, c);
            }
            if (l15 < 15) {
                #pragma unroll
                for (int t = 0; t < 4; ++t) {
                    int d = half * 64 + rt * 16 + lq * 4 + t;
                    int g = m * 1920 + d * 15 + l15;
                    arena[(g / 75) * 104 + (g % 75)] = f2bf(c[t]);
                }
            }
        }
    }
    __syncthreads();
    #pragma unroll
    for (int s = 0; s < 4; ++s) {
        int u = w * 4 + s;
        int rt = u & 7, ct = u >> 3;
        f32x4 c = zz;
        #pragma unroll
        for (int ks = 0; ks < 3; ++ks) {
            int k0 = ks * 32 + lq * 8;
            bf16x8 a  = *reinterpret_cast<const bf16x8*>(&arena[(rt * 16 + l15) * 104 + k0]);
            bf16x8 bh = *reinterpret_cast<const bf16x8*>(&maskThi[(ct * 16 + l15) * 96 + k0]);
            c = MFMA(a, bh, c);
        }
        #pragma unroll
        for (int t = 0; t < 4; ++t) {
            int dd = rt * 16 + lq * 4 + t;
            int col = ct * 16 + l15;
            msgB[(size_t)b * 8192 + dd * 64 + col] = f2bf(c[t] + btM[dd * 64 + col]);
        }
    }
}

// ---------------------------------------------------------------------------
// k2 v3 (unchanged from round 3): per (b,h), MFMA everywhere.
// ---------------------------------------------------------------------------
__global__ __launch_bounds__(512, 4) void k2_attn(
    const float* __restrict__ Kd, const float* __restrict__ Qd,
    ushort* msgB,  // read msg, write B (same slice per block)
    const float* __restrict__ R, const float* __restrict__ am,
    const ushort* __restrict__ WcatT, float* __restrict__ aw00)
{
    const int b = blockIdx.x >> 2, h = blockIdx.x & 3;
    const int tid = threadIdx.x;
    const int lane = tid & 63, w = tid >> 6;
    const int l15 = lane & 15, lq = lane >> 4;

    __shared__ ushort QTh[64 * 40], QTl[64 * 40];
    __shared__ ushort KTh[64 * 40], KTl[64 * 40];
    __shared__ ushort msgT[64 * 40];
    __shared__ float  ST[64 * 65];
    __shared__ ushort resS[128 * 72];
    __shared__ ushort awq[64 * 72];

    const size_t base = (size_t)b * 8192 + h * 2048;
    for (int i = tid; i < 2048; i += 512) {
        int d = i >> 6, n = i & 63;
        ushort hi, lo;
        split2(Qd[base + i], hi, lo); QTh[n * 40 + d] = hi; QTl[n * 40 + d] = lo;
        split2(Kd[base + i], hi, lo); KTh[n * 40 + d] = hi; KTl[n * 40 + d] = lo;
        msgT[n * 40 + d] = msgB[base + i];
    }
    __syncthreads();

    const float* Rb = R + ((size_t)b * Hh + h) * 4096;
    {
        int ti = w >> 1;
        bf16x8 ah = *reinterpret_cast<const bf16x8*>(&QTh[(ti * 16 + l15) * 40 + lq * 8]);
        bf16x8 al = *reinterpret_cast<const bf16x8*>(&QTl[(ti * 16 + l15) * 40 + lq * 8]);
        #pragma unroll
        for (int s = 0; s < 2; ++s) {
            int tj = (w & 1) * 2 + s;
            bf16x8 bh = *reinterpret_cast<const bf16x8*>(&KTh[(tj * 16 + l15) * 40 + lq * 8]);
            bf16x8 bl = *reinterpret_cast<const bf16x8*>(&KTl[(tj * 16 + l15) * 40 + lq * 8]);
            f32x4 c = {0.f, 0.f, 0.f, 0.f};
            c = MFMA(ah, bh, c); c = MFMA(ah, bl, c); c = MFMA(al, bh, c);
            #pragma unroll
            for (int r = 0; r < 4; ++r) {
                int i = ti * 16 + lq * 4 + r, j = tj * 16 + l15;
                ST[j * 65 + i] = Rb[i * 64 + j] + c[r] * RSQRT_DK;
            }
        }
    }
    {
        bf16x8 a = *reinterpret_cast<const bf16x8*>(WcatT + (w * 16 + l15) * 32 + lq * 8);
        #pragma unroll
        for (int nt = 0; nt < 4; ++nt) {
            bf16x8 bfr = *reinterpret_cast<const bf16x8*>(&msgT[(nt * 16 + l15) * 40 + lq * 8]);
            f32x4 c = {0.f, 0.f, 0.f, 0.f};
            c = MFMA(a, bfr, c);
            #pragma unroll
            for (int r = 0; r < 4; ++r)
                resS[(w * 16 + lq * 4 + r) * 72 + nt * 16 + l15] = f2bf(c[r]);
        }
    }
    __syncthreads();

    {
        int row = tid >> 3, part = tid & 7;
        float v[8]; float mx = -INFINITY;
        #pragma unroll
        for (int jj = 0; jj < 8; ++jj) { v[jj] = ST[(part * 8 + jj) * 65 + row]; mx = fmaxf(mx, v[jj]); }
        mx = fmaxf(mx, __shfl_xor(mx, 1));
        mx = fmaxf(mx, __shfl_xor(mx, 2));
        mx = fmaxf(mx, __shfl_xor(mx, 4));
        float s = 0.f;
        #pragma unroll
        for (int jj = 0; jj < 8; ++jj) { v[jj] = expf(v[jj] - mx); s += v[jj]; }
        s += __shfl_xor(s, 1); s += __shfl_xor(s, 2); s += __shfl_xor(s, 4);
        float inv = 1.f / s;
        #pragma unroll
        for (int jj = 0; jj < 8; ++jj) {
            float p = v[jj] * inv;
            ST[(part * 8 + jj) * 65 + row] = isnan(p) ? 0.f : p;
        }
    }
    __syncthreads();

    const int kt = w >> 2, it = w & 3;
    f32x4 accB = {0.f, 0.f, 0.f, 0.f};
    for (int q = 0; q < 4; ++q) {
        for (int e = tid; e < 4096; e += 512) {
            int i = e >> 6, j0 = e & 63;
            float p = ST[j0 * 65 + i] * am[i * 256 + q * 64 + j0];
            awq[i * 72 + j0] = f2bf(p);
            if (blockIdx.x == 0) aw00[i * 256 + q * 64 + j0] = p;
        }
        __syncthreads();
        #pragma unroll
        for (int ks = 0; ks < 2; ++ks) {
            int row = 4 * (kt * 16 + l15) + q;
            bf16x8 a   = *reinterpret_cast<const bf16x8*>(&resS[row * 72 + ks * 32 + lq * 8]);
            bf16x8 bfr = *reinterpret_cast<const bf16x8*>(&awq[(it * 16 + l15) * 72 + ks * 32 + lq * 8]);
            accB = MFMA(a, bfr, accB);
        }
        __syncthreads();
    }

    #pragma unroll
    for (int r = 0; r < 4; ++r) {
        int k = kt * 16 + lq * 4 + r, i = it * 16 + l15;
        float x = accB[r];
        float g = 0.5f * x * (1.f + erff(x * 0.70710678118654752f));
        msgB[base + k * 64 + i] = f2bf(g);
    }
}

// ---------------------------------------------------------------------------
// k3 (unchanged from round 3): per-b output projection + residual.
// ---------------------------------------------------------------------------
__global__ __launch_bounds__(512, 4) void k3_out(
    const ushort* __restrict__ Bbuf, const float* __restrict__ WW,
    const ushort* __restrict__ WBhi, const ushort* __restrict__ maskhi,
    const float* __restrict__ btB, const float* __restrict__ node,
    float* __restrict__ outp)
{
    const int b = blockIdx.x, tid = threadIdx.x;
    const int lane = tid & 63, w = tid >> 6, l15 = lane & 15, lq = lane >> 4;
    __shared__ ushort sB[128 * 66];
    __shared__ ushort wwh[64 * 17];
    __shared__ ushort t1[128 * 17];
    __shared__ ushort nm[32 * 66];

    for (int i = tid; i < 8192; i += 512) {
        int d = i >> 6, n = i & 63;
        sB[d * 66 + n] = Bbuf[(size_t)b * 8192 + i];
    }
    const f32x4 zz = {0.f, 0.f, 0.f, 0.f};
    f32x4 acc[4];
    for (int c = 0; c < 4; ++c) acc[c] = zz;
    __syncthreads();

    for (int m = 0; m < Mm; ++m) {
        for (int i = tid; i < 64 * 17; i += 512) {
            int n = i / 17, N = i - n * 17;
            wwh[i] = (N < 15) ? f2bf(WW[(((size_t)b * Mm + m) * 64 + n) * 15 + N]) : (ushort)0;
        }
        __syncthreads();
        {
            f32x4 c = zz;
            for (int ks = 0; ks < 2; ++ks) {
                int k0 = ks * 32 + (lq << 3);
                bf16x8 a, bh;
                #pragma unroll
                for (int t = 0; t < 8; ++t) {
                    a[t] = (short)sB[(w * 16 + l15) * 66 + k0 + t];
                    bh[t] = (short)wwh[(k0 + t) * 17 + l15];
                }
                c = MFMA(a, bh, c);
            }
            #pragma unroll
            for (int t = 0; t < 4; ++t)
                t1[(w * 16 + lq * 4 + t) * 17 + l15] = f2bf(c[t]);
        }
        __syncthreads();

        bf16x8 mfh;
        {
            int ct = w & 3;
            int k0 = lq << 3;
            #pragma unroll
            for (int t = 0; t < 8; ++t) {
                int kk = k0 + t;
                int row = (kk < 15) ? (m * 15 + kk) : 95;
                mfh[t] = (short)maskhi[row * 64 + ct * 16 + l15];
            }
        }
        for (int eb = 0; eb < 4; ++eb) {
            {
                int rtl = w >> 2, ct = w & 3;
                int e = eb * 32 + rtl * 16 + l15;
                int k0 = lq << 3;
                bf16x8 a;
                #pragma unroll
                for (int t = 0; t < 8; ++t) {
                    int kk = k0 + t;
                    int cc = (kk < 15) ? kk : 15;
                    a[t] = (short)t1[e * 17 + cc];
                }
                f32x4 c = zz;
                c = MFMA(a, mfh, c);
                #pragma unroll
                for (int t = 0; t < 4; ++t)
                    nm[(rtl * 16 + lq * 4 + t) * 66 + ct * 16 + l15] = f2bf(c[t]);
            }
            __syncthreads();
            {
                size_t aoff = (size_t)(w * 16 + l15) * 128 + eb * 32 + (lq << 3);
                bf16x8 a = *reinterpret_cast<const bf16x8*>(WBhi + m * 16384 + aoff);
                int k0 = lq << 3;
                #pragma unroll
                for (int ct = 0; ct < 4; ++ct) {
                    bf16x8 bh;
                    #pragma unroll
                    for (int t = 0; t < 8; ++t) bh[t] = (short)nm[(k0 + t) * 66 + ct * 16 + l15];
                    acc[ct] = MFMA(a, bh, acc[ct]);
                }
            }
            __syncthreads();
        }
    }
    #pragma unroll
    for (int ct = 0; ct < 4; ++ct) {
        #pragma unroll
        for (int t = 0; t < 4; ++t) {
            int d = w * 16 + lq * 4 + t;
            int col = ct * 16 + l15;
            size_t gi = (size_t)d * BN + b * 64 + col;
            outp[gi] = acc[ct][t] + btB[d * 64 + col] + node[gi];
        }
    }
}

extern "C" void kernel_launch(void* const* d_in, const int* in_sizes, int n_in,
                              void* d_out, int out_size, void* d_ws, size_t ws_size,
                              hipStream_t stream) {
    const float* node  = (const float*)d_in[0];
    const float* WW    = (const float*)d_in[1];
    const float* maskm = (const float*)d_in[2];
    const float* R     = (const float*)d_in[3];
    const float* am    = (const float*)d_in[4];
    const float* WK = (const float*)d_in[5];  const float* bK = (const float*)d_in[6];
    const float* WQ = (const float*)d_in[7];  const float* bQ = (const float*)d_in[8];
    const float* WM = (const float*)d_in[9];  const float* bM = (const float*)d_in[10];
    const float* WB = (const float*)d_in[11]; const float* bB = (const float*)d_in[12];
    const float* Wu = (const float*)d_in[13]; const float* Wd = (const float*)d_in[14];
    const float* Wl = (const float*)d_in[15]; const float* Wr = (const float*)d_in[16];

    float* out  = (float*)d_out;                 // K staging, then final out
    float* aw00 = out + (size_t)Dd * BN;         // disjoint tail of d_out

    char* W = (char*)d_ws;
    float*  Qbuf   = (float*)W;                          // 33,554,432 B
    ushort* msgB   = (ushort*)(W + 33554432);            // 16,777,216 B (msg, then B)
    ushort* WKhi   = (ushort*)(W + 50331648);
    ushort* WKlo   = WKhi + 81920;
    ushort* WQhi   = WKlo + 81920;
    ushort* WQlo   = WQhi + 81920;
    ushort* WMhi   = WQlo + 81920;
    ushort* WBhi   = WMhi + 81920;
    ushort* maskhi = WBhi + 81920;                       // 96*64 row-major
    ushort* masklo = maskhi + 6144;
    float*  btK    = (float*)(masklo + 6144);
    float*  btQ    = btK + 8192;
    float*  btM    = btQ + 8192;
    float*  btB    = btM + 8192;
    ushort* WcatT  = (ushort*)(btB + 8192);              // [128][32]
    ushort* maskThi = WcatT + 4096;                      // [64][96] transposed
    ushort* maskTlo = maskThi + 6144;

    k0_prep<<<512, 256, 0, stream>>>(maskm, WK, bK, WQ, bQ, WM, bM, WB, bB,
                                     Wu, Wd, Wl, Wr,
                                     WKhi, WKlo, WQhi, WQlo, WMhi, WBhi,
                                     maskhi, masklo, maskThi, maskTlo,
                                     btK, btQ, btM, btB, WcatT);
    k1_proj<<<Bb, 512, 0, stream>>>(node, WW, WKhi, WKlo, WQhi, WQlo, WMhi,
                                    maskThi, maskTlo, btK, btQ, btM,
                                    out, Qbuf, msgB);
    k2_attn<<<Bb * Hh, 512, 0, stream>>>(out, Qbuf, msgB, R, am, WcatT, aw00);
    k3_out<<<Bb, 512, 0, stream>>>(msgB, WW, WBhi, maskhi, btB, node, out);
}